// Round 14
// baseline (221.652 us; speedup 1.0000x reference)
//
#include <hip/hip_runtime.h>
#include <hip/hip_bf16.h>

// GatedNorm: out = xn * sigmoid(W_up @ silu(W_down @ xn)), xn = rmsnorm(x)
// B=4, S=4096, DIM=4096, R=128. All fp32 in/out.
//
// R13: R12 base (197us champion). One change: down_kernel KC 256 -> 512
// (8 chunks/8 barriers instead of 16; the per-chunk vmcnt(0)+barrier drain at
// 4 phase-locked blocks/CU is the m97-style stall). LDS 32.1 KB still allows
// the grid-capped 4 blocks/CU. launch_bounds(256,4) so v[8] staging doesn't
// spill (grid caps occupancy at 4 waves/SIMD anyway).
//  up_kernel: R12 verbatim (D-split 8, pinned x prefetch).

#define DIMX  4096
#define RLOW  128
#define BT    16
#define THREADS 256

typedef __attribute__((ext_vector_type(8))) short  bf16x8;
typedef __attribute__((ext_vector_type(4))) float  f32x4;

__device__ __forceinline__ unsigned short f2bf(float f) {
    unsigned int u = __float_as_uint(f);
    u = u + 0x7fffu + ((u >> 16) & 1u);     // RNE
    return (unsigned short)(u >> 16);
}
__device__ __forceinline__ float bf2f(unsigned short s) {
    return __uint_as_float((unsigned int)s << 16);
}
__device__ __forceinline__ float sigm(float v) { return 1.0f / (1.0f + __expf(-v)); }

__device__ __forceinline__ void cvt8_store(unsigned short* dst, float4 a, float4 b) {
    ushort4 u0, u1;
    u0.x = f2bf(a.x); u0.y = f2bf(a.y); u0.z = f2bf(a.z); u0.w = f2bf(a.w);
    u1.x = f2bf(b.x); u1.y = f2bf(b.y); u1.z = f2bf(b.z); u1.w = f2bf(b.w);
    *(ushort4*)dst = u0;
    *(ushort4*)(dst + 4) = u1;
}

// ---- prep: reorder weights into per-wave MFMA fragment order (bf16) --------
// wd_frag: frag = c*64 + ks*8 + nt*4 + wave  (c<16, ks<8, nt<2, wave<4)
//   element (lane,j): r = wave*32 + nt*16 + (lane&15), k = c*256+ks*32+8*(lane>>4)+j
//   note: indexed as kc = global k-chunk of 32 -> frag = kc*8 + nt*4 + wave.
// wu_frag: frag = d_tile*4 + ks  (d_tile<256, ks<4)
//   element (lane,j): row = d_tile*16 + (lane&15), col = ks*32 + 8*(lane>>4) + j
__global__ __launch_bounds__(THREADS)
void prep_weights_frag(const float* __restrict__ wd, const float* __restrict__ wu,
                       unsigned short* __restrict__ wd_frag,
                       unsigned short* __restrict__ wu_frag) {
    const int tg = blockIdx.x * THREADS + threadIdx.x;   // 0..131071
    if (tg < 65536) {
        const int frag = tg >> 6, lane = tg & 63;
        const int wave = frag & 3, nt = (frag >> 2) & 1, ks = (frag >> 3) & 7, c = frag >> 6;
        const int r = wave * 32 + nt * 16 + (lane & 15);
        const int k = c * 256 + ks * 32 + 8 * (lane >> 4);
        const float* src = wd + (long)r * DIMX + k;
        cvt8_store(wd_frag + ((long)frag << 9) + lane * 8,
                   *(const float4*)src, *(const float4*)(src + 4));
    } else {
        const int t2 = tg - 65536;
        const int frag = t2 >> 6, lane = t2 & 63;
        const int d_tile = frag >> 2, ks = frag & 3;
        const int row = d_tile * 16 + (lane & 15);
        const int col = ks * 32 + 8 * (lane >> 4);
        const float* src = wu + (long)row * RLOW + col;
        cvt8_store(wu_frag + ((long)frag << 9) + lane * 8,
                   *(const float4*)src, *(const float4*)(src + 4));
    }
}

// ---------------- kernel 1: down-proj + silu -> h_ws, invr_ws ----------------
// 256 threads, 4 waves; each wave computes 32 of the 128 r's.
// KC=512: 8 chunks, 8 barriers. LDS: 2 x [16][512] bf16 (32 KB, swizzled).
#define KC        512
#define NCH       (DIMX / KC)      // 8
#define XB_STRIDE 16384            // 16*512*2
#define INV1_OFF  (2 * XB_STRIDE)  // 32768
#define LDS1_BYTES (INV1_OFF + BT * 4)

__global__ __launch_bounds__(THREADS, 4)
void down_kernel(const float* __restrict__ x,
                 const unsigned short* __restrict__ wd_frag,  // fragment-ordered
                 unsigned short* __restrict__ h_ws,           // [ntok][R] bf16
                 float* __restrict__ invr_ws) {               // [ntok]
    extern __shared__ char smem[];
    const int tid  = threadIdx.x;
    const int lane = tid & 63;
    const int wave = tid >> 6;
    const int l15  = lane & 15;
    const int lq   = lane >> 4;

    const long tok0 = (long)blockIdx.x * BT;
    const float* __restrict__ xblk = x + tok0 * DIMX;

    const int srow = tid >> 4;      // token 0..15
    const int su   = tid & 15;

    float ss = 0.f;
    float4 v[8];

    // prologue: load + stage chunk 0 into buf 0 (row = 1024 B; swizzle spreads
    // 8 rows across distinct 16B slots: byte ^= (row&7)<<4)
    {
        const float4* src = (const float4*)(xblk + (long)srow * DIMX);
        #pragma unroll
        for (int j = 0; j < 8; ++j) v[j] = src[su + 16 * j];
        #pragma unroll
        for (int j = 0; j < 8; ++j) {
            float4 f = v[j];
            ss += f.x * f.x + f.y * f.y + f.z * f.z + f.w * f.w;
            ushort4 u4;
            u4.x = f2bf(f.x); u4.y = f2bf(f.y); u4.z = f2bf(f.z); u4.w = f2bf(f.w);
            int byte = (srow * 1024 + 8 * (su + 16 * j)) ^ ((srow & 7) << 4);
            *(ushort4*)(smem + byte) = u4;
        }
    }
    __syncthreads();

    f32x4 hacc[2] = {{0.f, 0.f, 0.f, 0.f}, {0.f, 0.f, 0.f, 0.f}};

    for (int c = 0; c < NCH; ++c) {
        if (c + 1 < NCH) {
            const float4* src = (const float4*)(xblk + (long)srow * DIMX + (c + 1) * KC);
            #pragma unroll
            for (int j = 0; j < 8; ++j) v[j] = src[su + 16 * j];
        }
        const char* xbuf = smem + (c & 1) * XB_STRIDE;
        // global k-chunk base for this c: kc = c*16 .. c*16+15; frag = kc*8+nt*4+wave
        const unsigned short* fb = wd_frag + (((long)c * 128) << 9) + lane * 8;
        #pragma unroll
        for (int ks = 0; ks < KC / 32; ++ks) {
            const int kk = ks * 32 + 8 * lq;
            const int abyte = (l15 * 1024 + kk * 2) ^ ((l15 & 7) << 4);
            bf16x8 a = *(const bf16x8*)(xbuf + abyte);
            #pragma unroll
            for (int nt = 0; nt < 2; ++nt) {
                bf16x8 b = *(const bf16x8*)(fb + ((long)(ks * 8 + nt * 4 + wave) << 9));
                hacc[nt] = __builtin_amdgcn_mfma_f32_16x16x32_bf16(a, b, hacc[nt], 0, 0, 0);
            }
        }
        if (c + 1 < NCH) {
            char* nbuf = smem + ((c + 1) & 1) * XB_STRIDE;
            #pragma unroll
            for (int j = 0; j < 8; ++j) {
                float4 f = v[j];
                ss += f.x * f.x + f.y * f.y + f.z * f.z + f.w * f.w;
                ushort4 u4;
                u4.x = f2bf(f.x); u4.y = f2bf(f.y); u4.z = f2bf(f.z); u4.w = f2bf(f.w);
                int byte = (srow * 1024 + 8 * (su + 16 * j)) ^ ((srow & 7) << 4);
                *(ushort4*)(nbuf + byte) = u4;
            }
        }
        __syncthreads();
    }

    // inv_rms per token row
    #pragma unroll
    for (int m = 1; m < 16; m <<= 1) ss += __shfl_xor(ss, m, 64);
    if (su == 0) {
        float invr = rsqrtf(ss * (1.0f / DIMX) + 1.1920929e-07f);
        *(float*)(smem + INV1_OFF + srow * 4) = invr;
        invr_ws[tok0 + srow] = invr;
    }
    __syncthreads();

    // h = silu(hpre * invr) -> h_ws (bf16); wave w, frag nt own r = w*32+nt*16+l15
    #pragma unroll
    for (int nt = 0; nt < 2; ++nt) {
        const int r = wave * 32 + nt * 16 + l15;
        #pragma unroll
        for (int i = 0; i < 4; ++i) {
            const int t = 4 * lq + i;
            float invr = *(const float*)(smem + INV1_OFF + t * 4);
            float hp = hacc[nt][i] * invr;
            float hs = hp * sigm(hp);
            h_ws[(tok0 + t) * RLOW + r] = f2bf(hs);
        }
    }
}

// ---------------- kernel 2: up-proj + sigmoid gate + multiply ----------------
// R12 verbatim. grid = nblk*8. Block: 16 tokens x 512 cols; wave: ONE 128-col
// super-group. x prefetch pinned with sched_barrier(0); gate (x invr) bounced
// through wave-private bf16 slab for token-contiguous stores.
#define SLAB_US   2176          // ushorts per wave slab: 16 rows * 136
#define UP_LDS_BYTES (4 * SLAB_US * 2)   // 17408

__global__ __launch_bounds__(THREADS, 4)
void up_kernel(const float* __restrict__ x,
               const unsigned short* __restrict__ wu_frag,  // fragment-ordered
               const unsigned short* __restrict__ h_ws,     // [ntok][R] bf16
               const float* __restrict__ invr_ws,           // [ntok]
               float* __restrict__ out) {
    extern __shared__ char smem[];
    const int tid  = threadIdx.x;
    const int lane = tid & 63;
    const int wave = tid >> 6;
    const int l15  = lane & 15;
    const int lq   = lane >> 4;

    const int tb   = blockIdx.x >> 3;
    const int dblk = blockIdx.x & 7;
    const long tok0 = (long)tb * BT;

    // B fragments: h^T for these 16 tokens (lane col = token l15)
    bf16x8 hb[4];
    #pragma unroll
    for (int ks = 0; ks < 4; ++ks)
        hb[ks] = *(const bf16x8*)(h_ws + (tok0 + l15) * RLOW + ks * 32 + 8 * lq);
    const float invr_t = invr_ws[tok0 + l15];

    unsigned short* slab = (unsigned short*)smem + wave * SLAB_US;  // [16][136]
    const int token_lo = lane >> 5;           // 0/1
    const int cw = (lane & 31) * 4;
    const int colbase = dblk * 512 + wave * 128;
    const int dt0 = colbase >> 4;

    // issue x loads; fence so the scheduler cannot sink them under the tiles
    float4 xf[8];
    #pragma unroll
    for (int it = 0; it < 8; ++it)
        xf[it] = *(const float4*)(x + (tok0 + 2 * it + token_lo) * DIMX + colbase + cw);
    __builtin_amdgcn_sched_barrier(0);

    // 8 tiles (16 tok x 16 col): MFMA, sigmoid*invr, transpose-write slab
    #pragma unroll
    for (int tg = 0; tg < 8; ++tg) {
        bf16x8 wa[4];
        #pragma unroll
        for (int ks = 0; ks < 4; ++ks)
            wa[ks] = *(const bf16x8*)(wu_frag + ((long)((dt0 + tg) * 4 + ks) << 9) + lane * 8);
        f32x4 acc = {0.f, 0.f, 0.f, 0.f};
        #pragma unroll
        for (int ks = 0; ks < 4; ++ks)
            acc = __builtin_amdgcn_mfma_f32_16x16x32_bf16(wa[ks], hb[ks], acc, 0, 0, 0);
        ushort4 g4;                      // token = l15, d = colbase+tg*16+4lq+i
        g4.x = f2bf(sigm(acc[0]) * invr_t);
        g4.y = f2bf(sigm(acc[1]) * invr_t);
        g4.z = f2bf(sigm(acc[2]) * invr_t);
        g4.w = f2bf(sigm(acc[3]) * invr_t);
        *(ushort4*)(slab + l15 * 136 + tg * 16 + lq * 4) = g4;
    }

    // epilogue: read slab token-major (wave-private; lgkmcnt orders ws->rs),
    // combine with prefetched x, store contiguous.
    #pragma unroll
    for (int it = 0; it < 8; ++it) {
        const int token = 2 * it + token_lo;
        ushort4 gv = *(const ushort4*)(slab + token * 136 + cw);
        float4 o;
        o.x = xf[it].x * bf2f(gv.x);
        o.y = xf[it].y * bf2f(gv.y);
        o.z = xf[it].z * bf2f(gv.z);
        o.w = xf[it].w * bf2f(gv.w);
        *(float4*)(out + (tok0 + token) * DIMX + colbase + cw) = o;
    }
}

// ---------------- fallback: fused kernel with inline fp32->bf16 -------------
#define FKC   512
#define FNCH  (DIMX / FKC)
#define FXB_STRIDE 16384
#define HP        136
#define H_OFF     (2 * FXB_STRIDE)
#define INV_OFF   (H_OFF + BT * HP * 2)
#define LDSF_BYTES (INV_OFF + BT * 4)

__device__ __forceinline__ bf16x8 load_w8_f32(const float* __restrict__ wf, long off) {
    float4 a = *(const float4*)(wf + off);
    float4 b = *(const float4*)(wf + off + 4);
    bf16x8 r;
    r[0] = (short)f2bf(a.x); r[1] = (short)f2bf(a.y);
    r[2] = (short)f2bf(a.z); r[3] = (short)f2bf(a.w);
    r[4] = (short)f2bf(b.x); r[5] = (short)f2bf(b.y);
    r[6] = (short)f2bf(b.z); r[7] = (short)f2bf(b.w);
    return r;
}

__global__ __launch_bounds__(THREADS)
void fused_fallback(const float* __restrict__ x,
                    const float* __restrict__ wd_f32,
                    const float* __restrict__ wu_f32,
                    float* __restrict__ out) {
    extern __shared__ char smem[];
    const int tid  = threadIdx.x;
    const int lane = tid & 63;
    const int wave = tid >> 6;
    const int l15  = lane & 15;
    const int lq   = lane >> 4;
    const long tok0 = (long)blockIdx.x * BT;
    const float* __restrict__ xblk = x + tok0 * DIMX;
    float* __restrict__ outblk = out + tok0 * DIMX;
    const int srow = tid >> 4;
    const int su   = tid & 15;
    float ss = 0.f;
    float4 v[8];
    {
        const float4* src = (const float4*)(xblk + (long)srow * DIMX);
        #pragma unroll
        for (int j = 0; j < 8; ++j) v[j] = src[su + 16 * j];
        #pragma unroll
        for (int j = 0; j < 8; ++j) {
            float4 f = v[j];
            ss += f.x * f.x + f.y * f.y + f.z * f.z + f.w * f.w;
            ushort4 u4;
            u4.x = f2bf(f.x); u4.y = f2bf(f.y); u4.z = f2bf(f.z); u4.w = f2bf(f.w);
            int byte = (srow * 1024 + 8 * (su + 16 * j)) ^ ((srow & 7) << 4);
            *(ushort4*)(smem + byte) = u4;
        }
    }
    __syncthreads();
    f32x4 hacc[2] = {{0.f, 0.f, 0.f, 0.f}, {0.f, 0.f, 0.f, 0.f}};
    const int n0w = wave * 32;
    for (int c = 0; c < FNCH; ++c) {
        if (c + 1 < FNCH) {
            const float4* src = (const float4*)(xblk + (long)srow * DIMX + (c + 1) * FKC);
            #pragma unroll
            for (int j = 0; j < 8; ++j) v[j] = src[su + 16 * j];
        }
        const char* xbuf = smem + (c & 1) * FXB_STRIDE;
        #pragma unroll 4
        for (int ks = 0; ks < FKC / 32; ++ks) {
            const int kk = ks * 32 + 8 * lq;
            const int abyte = (l15 * 1024 + kk * 2) ^ ((l15 & 7) << 4);
            bf16x8 a = *(const bf16x8*)(xbuf + abyte);
            const long kg = (long)c * FKC + kk;
            #pragma unroll
            for (int nt = 0; nt < 2; ++nt) {
                const int r = n0w + nt * 16 + l15;
                bf16x8 b = load_w8_f32(wd_f32, (long)r * DIMX + kg);
                hacc[nt] = __builtin_amdgcn_mfma_f32_16x16x32_bf16(a, b, hacc[nt], 0, 0, 0);
            }
        }
        if (c + 1 < FNCH) {
            char* nbuf = smem + ((c + 1) & 1) * FXB_STRIDE;
            #pragma unroll
            for (int j = 0; j < 8; ++j) {
                float4 f = v[j];
                ss += f.x * f.x + f.y * f.y + f.z * f.z + f.w * f.w;
                ushort4 u4;
                u4.x = f2bf(f.x); u4.y = f2bf(f.y); u4.z = f2bf(f.z); u4.w = f2bf(f.w);
                int byte = (srow * 1024 + 8 * (su + 16 * j)) ^ ((srow & 7) << 4);
                *(ushort4*)(nbuf + byte) = u4;
            }
        }
        __syncthreads();
    }
    #pragma unroll
    for (int m = 1; m < 16; m <<= 1) ss += __shfl_xor(ss, m, 64);
    if (su == 0) {
        float invr = rsqrtf(ss * (1.0f / DIMX) + 1.1920929e-07f);
        *(float*)(smem + INV_OFF + srow * 4) = invr;
    }
    __syncthreads();
    #pragma unroll
    for (int nt = 0; nt < 2; ++nt) {
        const int r = n0w + nt * 16 + l15;
        #pragma unroll
        for (int i = 0; i < 4; ++i) {
            const int t = 4 * lq + i;
            float invr = *(const float*)(smem + INV_OFF + t * 4);
            float hp = hacc[nt][i] * invr;
            float hs = hp * sigm(hp);
            *(unsigned short*)(smem + H_OFF + (t * HP + r) * 2) = f2bf(hs);
        }
    }
    __syncthreads();
    bf16x8 hb[4];
    #pragma unroll
    for (int ks = 0; ks < 4; ++ks)
        hb[ks] = *(const bf16x8*)(smem + H_OFF + (l15 * HP + ks * 32 + 8 * lq) * 2);
    const float invr_t = *(const float*)(smem + INV_OFF + l15 * 4);
    const int t = l15;
    const int wbase = wave * (DIMX / 4);
    for (int g = 0; g < 16; ++g) {
        const int d0 = wbase + g * 64;
        bf16x8 wa[4][4];
        #pragma unroll
        for (int tt = 0; tt < 4; ++tt) {
            const int drow = d0 + tt * 16 + l15;
            #pragma unroll
            for (int ks = 0; ks < 4; ++ks)
                wa[tt][ks] = load_w8_f32(wu_f32, (long)drow * RLOW + ks * 32 + 8 * lq);
        }
        f32x4 acc[4] = {{0.f,0.f,0.f,0.f},{0.f,0.f,0.f,0.f},{0.f,0.f,0.f,0.f},{0.f,0.f,0.f,0.f}};
        #pragma unroll
        for (int ks = 0; ks < 4; ++ks)
            #pragma unroll
            for (int tt = 0; tt < 4; ++tt)
                acc[tt] = __builtin_amdgcn_mfma_f32_16x16x32_bf16(wa[tt][ks], hb[ks], acc[tt], 0, 0, 0);
        #pragma unroll
        for (int tt = 0; tt < 4; ++tt) {
            const int dc = d0 + tt * 16 + 4 * lq;
            float4 xf = *(const float4*)(xblk + (long)t * DIMX + dc);
            float4 o;
            o.x = xf.x * invr_t * sigm(acc[tt][0]);
            o.y = xf.y * invr_t * sigm(acc[tt][1]);
            o.z = xf.z * invr_t * sigm(acc[tt][2]);
            o.w = xf.w * invr_t * sigm(acc[tt][3]);
            *(float4*)(outblk + (long)t * DIMX + dc) = o;
        }
    }
}

extern "C" void kernel_launch(void* const* d_in, const int* in_sizes, int n_in,
                              void* d_out, int out_size, void* d_ws, size_t ws_size,
                              hipStream_t stream) {
    const float* x  = (const float*)d_in[0];
    const float* wd = (const float*)d_in[1];   // [128][4096]
    const float* wu = (const float*)d_in[2];   // [4096][128]
    float* out = (float*)d_out;

    const int ntok = in_sizes[0] / DIMX;       // 16384
    const int nblk = ntok / BT;                // 1024

    // ws: wd_frag (1MB) | wu_frag (1MB) | h_ws (4MB) | invr_ws (64KB)
    const size_t need = (size_t)2 * RLOW * DIMX * 2
                      + (size_t)ntok * RLOW * 2
                      + (size_t)ntok * 4;
    if (ws_size >= need) {
        unsigned short* wd_frag = (unsigned short*)d_ws;
        unsigned short* wu_frag = wd_frag + (size_t)RLOW * DIMX;
        unsigned short* h_ws    = wu_frag + (size_t)RLOW * DIMX;
        float*          invr_ws = (float*)(h_ws + (size_t)ntok * RLOW);
        prep_weights_frag<<<512, THREADS, 0, stream>>>(wd, wu, wd_frag, wu_frag);
        down_kernel<<<nblk, THREADS, LDS1_BYTES, stream>>>(x, wd_frag, h_ws, invr_ws);
        up_kernel<<<nblk * 8, THREADS, UP_LDS_BYTES, stream>>>(x, wu_frag, h_ws, invr_ws, out);
    } else {
        fused_fallback<<<nblk, THREADS, LDSF_BYTES, stream>>>(x, wd, wu, out);
    }
}

// Round 15
// 196.607 us; speedup vs baseline: 1.1274x; 1.1274x over previous
//
#include <hip/hip_runtime.h>
#include <hip/hip_bf16.h>

// GatedNorm: out = xn * sigmoid(W_up @ silu(W_down @ xn)), xn = rmsnorm(x)
// B=4, S=4096, DIM=4096, R=128. All fp32 in/out.
//
// R14 = R12 verbatim (197.3us champion restore).
// Structure: prep (weights -> bf16 MFMA-fragment order, 1KB contiguous L2
// reads per wave fragment) + down_kernel (R4 form: 256thr, KC=256 double-
// buffered x staging, swizzled LDS) + up_kernel (D-split 8, one 128-col
// super-group per wave, sched_barrier-pinned x prefetch, wave-private bf16
// slab transpose for token-contiguous x-reread/out-store).
// Rejected by measurement: fused 1-kernel (R0/R7), 512-thr down (R5/R6),
// KC=512 down (R13), register wa-pipelining (R10/R11 - allocator spills),
// VGPR squeezes (R5), 4-way D-split w/ sg loop (R4/R9 - superseded by R12).

#define DIMX  4096
#define RLOW  128
#define BT    16
#define THREADS 256

typedef __attribute__((ext_vector_type(8))) short  bf16x8;
typedef __attribute__((ext_vector_type(4))) float  f32x4;

__device__ __forceinline__ unsigned short f2bf(float f) {
    unsigned int u = __float_as_uint(f);
    u = u + 0x7fffu + ((u >> 16) & 1u);     // RNE
    return (unsigned short)(u >> 16);
}
__device__ __forceinline__ float bf2f(unsigned short s) {
    return __uint_as_float((unsigned int)s << 16);
}
__device__ __forceinline__ float sigm(float v) { return 1.0f / (1.0f + __expf(-v)); }

__device__ __forceinline__ void cvt8_store(unsigned short* dst, float4 a, float4 b) {
    ushort4 u0, u1;
    u0.x = f2bf(a.x); u0.y = f2bf(a.y); u0.z = f2bf(a.z); u0.w = f2bf(a.w);
    u1.x = f2bf(b.x); u1.y = f2bf(b.y); u1.z = f2bf(b.z); u1.w = f2bf(b.w);
    *(ushort4*)dst = u0;
    *(ushort4*)(dst + 4) = u1;
}

// ---- prep: reorder weights into per-wave MFMA fragment order (bf16) --------
// wd_frag: frag = c*64 + ks*8 + nt*4 + wave  (c<16, ks<8, nt<2, wave<4)
//   element (lane,j): r = wave*32 + nt*16 + (lane&15), k = c*256+ks*32+8*(lane>>4)+j
// wu_frag: frag = d_tile*4 + ks  (d_tile<256, ks<4)
//   element (lane,j): row = d_tile*16 + (lane&15), col = ks*32 + 8*(lane>>4) + j
__global__ __launch_bounds__(THREADS)
void prep_weights_frag(const float* __restrict__ wd, const float* __restrict__ wu,
                       unsigned short* __restrict__ wd_frag,
                       unsigned short* __restrict__ wu_frag) {
    const int tg = blockIdx.x * THREADS + threadIdx.x;   // 0..131071
    if (tg < 65536) {
        const int frag = tg >> 6, lane = tg & 63;
        const int wave = frag & 3, nt = (frag >> 2) & 1, ks = (frag >> 3) & 7, c = frag >> 6;
        const int r = wave * 32 + nt * 16 + (lane & 15);
        const int k = c * 256 + ks * 32 + 8 * (lane >> 4);
        const float* src = wd + (long)r * DIMX + k;
        cvt8_store(wd_frag + ((long)frag << 9) + lane * 8,
                   *(const float4*)src, *(const float4*)(src + 4));
    } else {
        const int t2 = tg - 65536;
        const int frag = t2 >> 6, lane = t2 & 63;
        const int d_tile = frag >> 2, ks = frag & 3;
        const int row = d_tile * 16 + (lane & 15);
        const int col = ks * 32 + 8 * (lane >> 4);
        const float* src = wu + (long)row * RLOW + col;
        cvt8_store(wu_frag + ((long)frag << 9) + lane * 8,
                   *(const float4*)src, *(const float4*)(src + 4));
    }
}

// ---------------- kernel 1: down-proj + silu -> h_ws, invr_ws ----------------
// R4/R9 verbatim. 256 threads, 4 waves; each wave computes 32 of the 128 r's.
// LDS: 2 x [16][256] bf16 (16 KB, swizzled) + invr[16]
#define KC        256
#define NCH       (DIMX / KC)      // 16
#define XB_STRIDE 8192             // 16*256*2
#define INV1_OFF  (2 * XB_STRIDE)  // 16384
#define LDS1_BYTES (INV1_OFF + BT * 4)

__global__ __launch_bounds__(THREADS, 6)
void down_kernel(const float* __restrict__ x,
                 const unsigned short* __restrict__ wd_frag,  // fragment-ordered
                 unsigned short* __restrict__ h_ws,           // [ntok][R] bf16
                 float* __restrict__ invr_ws) {               // [ntok]
    extern __shared__ char smem[];
    const int tid  = threadIdx.x;
    const int lane = tid & 63;
    const int wave = tid >> 6;
    const int l15  = lane & 15;
    const int lq   = lane >> 4;

    const long tok0 = (long)blockIdx.x * BT;
    const float* __restrict__ xblk = x + tok0 * DIMX;

    const int srow = tid >> 4;      // token 0..15
    const int su   = tid & 15;

    float ss = 0.f;
    float4 v[4];

    // prologue: load + stage chunk 0 into buf 0
    {
        const float4* src = (const float4*)(xblk + (long)srow * DIMX);
        #pragma unroll
        for (int j = 0; j < 4; ++j) v[j] = src[su + 16 * j];
        #pragma unroll
        for (int j = 0; j < 4; ++j) {
            float4 f = v[j];
            ss += f.x * f.x + f.y * f.y + f.z * f.z + f.w * f.w;
            ushort4 u4;
            u4.x = f2bf(f.x); u4.y = f2bf(f.y); u4.z = f2bf(f.z); u4.w = f2bf(f.w);
            int byte = (srow * 512 + 8 * (su + 16 * j)) ^ ((srow & 7) << 4);
            *(ushort4*)(smem + byte) = u4;
        }
    }
    __syncthreads();

    f32x4 hacc[2] = {{0.f, 0.f, 0.f, 0.f}, {0.f, 0.f, 0.f, 0.f}};

    for (int c = 0; c < NCH; ++c) {
        if (c + 1 < NCH) {
            const float4* src = (const float4*)(xblk + (long)srow * DIMX + (c + 1) * KC);
            #pragma unroll
            for (int j = 0; j < 4; ++j) v[j] = src[su + 16 * j];
        }
        const char* xbuf = smem + (c & 1) * XB_STRIDE;
        const unsigned short* fb = wd_frag + (((long)c * 64) << 9) + lane * 8;
        #pragma unroll
        for (int ks = 0; ks < KC / 32; ++ks) {
            const int kk = ks * 32 + 8 * lq;
            const int abyte = (l15 * 512 + kk * 2) ^ ((l15 & 7) << 4);
            bf16x8 a = *(const bf16x8*)(xbuf + abyte);
            #pragma unroll
            for (int nt = 0; nt < 2; ++nt) {
                bf16x8 b = *(const bf16x8*)(fb + ((long)(ks * 8 + nt * 4 + wave) << 9));
                hacc[nt] = __builtin_amdgcn_mfma_f32_16x16x32_bf16(a, b, hacc[nt], 0, 0, 0);
            }
        }
        if (c + 1 < NCH) {
            char* nbuf = smem + ((c + 1) & 1) * XB_STRIDE;
            #pragma unroll
            for (int j = 0; j < 4; ++j) {
                float4 f = v[j];
                ss += f.x * f.x + f.y * f.y + f.z * f.z + f.w * f.w;
                ushort4 u4;
                u4.x = f2bf(f.x); u4.y = f2bf(f.y); u4.z = f2bf(f.z); u4.w = f2bf(f.w);
                int byte = (srow * 512 + 8 * (su + 16 * j)) ^ ((srow & 7) << 4);
                *(ushort4*)(nbuf + byte) = u4;
            }
        }
        __syncthreads();
    }

    // inv_rms per token row
    #pragma unroll
    for (int m = 1; m < 16; m <<= 1) ss += __shfl_xor(ss, m, 64);
    if (su == 0) {
        float invr = rsqrtf(ss * (1.0f / DIMX) + 1.1920929e-07f);
        *(float*)(smem + INV1_OFF + srow * 4) = invr;
        invr_ws[tok0 + srow] = invr;
    }
    __syncthreads();

    // h = silu(hpre * invr) -> h_ws (bf16); wave w, frag nt own r = w*32+nt*16+l15
    #pragma unroll
    for (int nt = 0; nt < 2; ++nt) {
        const int r = wave * 32 + nt * 16 + l15;
        #pragma unroll
        for (int i = 0; i < 4; ++i) {
            const int t = 4 * lq + i;
            float invr = *(const float*)(smem + INV1_OFF + t * 4);
            float hp = hacc[nt][i] * invr;
            float hs = hp * sigm(hp);
            h_ws[(tok0 + t) * RLOW + r] = f2bf(hs);
        }
    }
}

// ---------------- kernel 2: up-proj + sigmoid gate + multiply ----------------
// grid = nblk*8. Block: 16 tokens x 512 cols; wave: ONE 128-col super-group.
// x prefetch pinned with sched_barrier(0) (R9 mechanism), hides under the
// 8-tile MFMA chain. Gate (x invr) bounced through wave-private bf16 slab for
// token-contiguous stores. No sg loop -> minimal live ranges.
#define SLAB_US   2176          // ushorts per wave slab: 16 rows * 136
#define UP_LDS_BYTES (4 * SLAB_US * 2)   // 17408

__global__ __launch_bounds__(THREADS, 4)
void up_kernel(const float* __restrict__ x,
               const unsigned short* __restrict__ wu_frag,  // fragment-ordered
               const unsigned short* __restrict__ h_ws,     // [ntok][R] bf16
               const float* __restrict__ invr_ws,           // [ntok]
               float* __restrict__ out) {
    extern __shared__ char smem[];
    const int tid  = threadIdx.x;
    const int lane = tid & 63;
    const int wave = tid >> 6;
    const int l15  = lane & 15;
    const int lq   = lane >> 4;

    const int tb   = blockIdx.x >> 3;
    const int dblk = blockIdx.x & 7;
    const long tok0 = (long)tb * BT;

    // B fragments: h^T for these 16 tokens (lane col = token l15)
    bf16x8 hb[4];
    #pragma unroll
    for (int ks = 0; ks < 4; ++ks)
        hb[ks] = *(const bf16x8*)(h_ws + (tok0 + l15) * RLOW + ks * 32 + 8 * lq);
    const float invr_t = invr_ws[tok0 + l15];

    unsigned short* slab = (unsigned short*)smem + wave * SLAB_US;  // [16][136]
    const int token_lo = lane >> 5;           // 0/1
    const int cw = (lane & 31) * 4;
    const int colbase = dblk * 512 + wave * 128;
    const int dt0 = colbase >> 4;

    // issue x loads; fence so the scheduler cannot sink them under the tiles
    float4 xf[8];
    #pragma unroll
    for (int it = 0; it < 8; ++it)
        xf[it] = *(const float4*)(x + (tok0 + 2 * it + token_lo) * DIMX + colbase + cw);
    __builtin_amdgcn_sched_barrier(0);

    // 8 tiles (16 tok x 16 col): MFMA, sigmoid*invr, transpose-write slab
    #pragma unroll
    for (int tg = 0; tg < 8; ++tg) {
        bf16x8 wa[4];
        #pragma unroll
        for (int ks = 0; ks < 4; ++ks)
            wa[ks] = *(const bf16x8*)(wu_frag + ((long)((dt0 + tg) * 4 + ks) << 9) + lane * 8);
        f32x4 acc = {0.f, 0.f, 0.f, 0.f};
        #pragma unroll
        for (int ks = 0; ks < 4; ++ks)
            acc = __builtin_amdgcn_mfma_f32_16x16x32_bf16(wa[ks], hb[ks], acc, 0, 0, 0);
        ushort4 g4;                      // token = l15, d = colbase+tg*16+4lq+i
        g4.x = f2bf(sigm(acc[0]) * invr_t);
        g4.y = f2bf(sigm(acc[1]) * invr_t);
        g4.z = f2bf(sigm(acc[2]) * invr_t);
        g4.w = f2bf(sigm(acc[3]) * invr_t);
        *(ushort4*)(slab + l15 * 136 + tg * 16 + lq * 4) = g4;
    }

    // epilogue: read slab token-major (wave-private; lgkmcnt orders ws->rs),
    // combine with prefetched x, store contiguous.
    #pragma unroll
    for (int it = 0; it < 8; ++it) {
        const int token = 2 * it + token_lo;
        ushort4 gv = *(const ushort4*)(slab + token * 136 + cw);
        float4 o;
        o.x = xf[it].x * bf2f(gv.x);
        o.y = xf[it].y * bf2f(gv.y);
        o.z = xf[it].z * bf2f(gv.z);
        o.w = xf[it].w * bf2f(gv.w);
        *(float4*)(out + (tok0 + token) * DIMX + colbase + cw) = o;
    }
}

// ---------------- fallback: fused kernel with inline fp32->bf16 -------------
#define FKC   512
#define FNCH  (DIMX / FKC)
#define FXB_STRIDE 16384
#define HP        136
#define H_OFF     (2 * FXB_STRIDE)
#define INV_OFF   (H_OFF + BT * HP * 2)
#define LDSF_BYTES (INV_OFF + BT * 4)

__device__ __forceinline__ bf16x8 load_w8_f32(const float* __restrict__ wf, long off) {
    float4 a = *(const float4*)(wf + off);
    float4 b = *(const float4*)(wf + off + 4);
    bf16x8 r;
    r[0] = (short)f2bf(a.x); r[1] = (short)f2bf(a.y);
    r[2] = (short)f2bf(a.z); r[3] = (short)f2bf(a.w);
    r[4] = (short)f2bf(b.x); r[5] = (short)f2bf(b.y);
    r[6] = (short)f2bf(b.z); r[7] = (short)f2bf(b.w);
    return r;
}

__global__ __launch_bounds__(THREADS)
void fused_fallback(const float* __restrict__ x,
                    const float* __restrict__ wd_f32,
                    const float* __restrict__ wu_f32,
                    float* __restrict__ out) {
    extern __shared__ char smem[];
    const int tid  = threadIdx.x;
    const int lane = tid & 63;
    const int wave = tid >> 6;
    const int l15  = lane & 15;
    const int lq   = lane >> 4;
    const long tok0 = (long)blockIdx.x * BT;
    const float* __restrict__ xblk = x + tok0 * DIMX;
    float* __restrict__ outblk = out + tok0 * DIMX;
    const int srow = tid >> 4;
    const int su   = tid & 15;
    float ss = 0.f;
    float4 v[8];
    {
        const float4* src = (const float4*)(xblk + (long)srow * DIMX);
        #pragma unroll
        for (int j = 0; j < 8; ++j) v[j] = src[su + 16 * j];
        #pragma unroll
        for (int j = 0; j < 8; ++j) {
            float4 f = v[j];
            ss += f.x * f.x + f.y * f.y + f.z * f.z + f.w * f.w;
            ushort4 u4;
            u4.x = f2bf(f.x); u4.y = f2bf(f.y); u4.z = f2bf(f.z); u4.w = f2bf(f.w);
            int byte = (srow * 1024 + 8 * (su + 16 * j)) ^ ((srow & 7) << 4);
            *(ushort4*)(smem + byte) = u4;
        }
    }
    __syncthreads();
    f32x4 hacc[2] = {{0.f, 0.f, 0.f, 0.f}, {0.f, 0.f, 0.f, 0.f}};
    const int n0w = wave * 32;
    for (int c = 0; c < FNCH; ++c) {
        if (c + 1 < FNCH) {
            const float4* src = (const float4*)(xblk + (long)srow * DIMX + (c + 1) * FKC);
            #pragma unroll
            for (int j = 0; j < 8; ++j) v[j] = src[su + 16 * j];
        }
        const char* xbuf = smem + (c & 1) * FXB_STRIDE;
        #pragma unroll 4
        for (int ks = 0; ks < FKC / 32; ++ks) {
            const int kk = ks * 32 + 8 * lq;
            const int abyte = (l15 * 1024 + kk * 2) ^ ((l15 & 7) << 4);
            bf16x8 a = *(const bf16x8*)(xbuf + abyte);
            const long kg = (long)c * FKC + kk;
            #pragma unroll
            for (int nt = 0; nt < 2; ++nt) {
                const int r = n0w + nt * 16 + l15;
                bf16x8 b = load_w8_f32(wd_f32, (long)r * DIMX + kg);
                hacc[nt] = __builtin_amdgcn_mfma_f32_16x16x32_bf16(a, b, hacc[nt], 0, 0, 0);
            }
        }
        if (c + 1 < FNCH) {
            char* nbuf = smem + ((c + 1) & 1) * FXB_STRIDE;
            #pragma unroll
            for (int j = 0; j < 8; ++j) {
                float4 f = v[j];
                ss += f.x * f.x + f.y * f.y + f.z * f.z + f.w * f.w;
                ushort4 u4;
                u4.x = f2bf(f.x); u4.y = f2bf(f.y); u4.z = f2bf(f.z); u4.w = f2bf(f.w);
                int byte = (srow * 1024 + 8 * (su + 16 * j)) ^ ((srow & 7) << 4);
                *(ushort4*)(nbuf + byte) = u4;
            }
        }
        __syncthreads();
    }
    #pragma unroll
    for (int m = 1; m < 16; m <<= 1) ss += __shfl_xor(ss, m, 64);
    if (su == 0) {
        float invr = rsqrtf(ss * (1.0f / DIMX) + 1.1920929e-07f);
        *(float*)(smem + INV_OFF + srow * 4) = invr;
    }
    __syncthreads();
    #pragma unroll
    for (int nt = 0; nt < 2; ++nt) {
        const int r = n0w + nt * 16 + l15;
        #pragma unroll
        for (int i = 0; i < 4; ++i) {
            const int t = 4 * lq + i;
            float invr = *(const float*)(smem + INV_OFF + t * 4);
            float hp = hacc[nt][i] * invr;
            float hs = hp * sigm(hp);
            *(unsigned short*)(smem + H_OFF + (t * HP + r) * 2) = f2bf(hs);
        }
    }
    __syncthreads();
    bf16x8 hb[4];
    #pragma unroll
    for (int ks = 0; ks < 4; ++ks)
        hb[ks] = *(const bf16x8*)(smem + H_OFF + (l15 * HP + ks * 32 + 8 * lq) * 2);
    const float invr_t = *(const float*)(smem + INV_OFF + l15 * 4);
    const int t = l15;
    const int wbase = wave * (DIMX / 4);
    for (int g = 0; g < 16; ++g) {
        const int d0 = wbase + g * 64;
        bf16x8 wa[4][4];
        #pragma unroll
        for (int tt = 0; tt < 4; ++tt) {
            const int drow = d0 + tt * 16 + l15;
            #pragma unroll
            for (int ks = 0; ks < 4; ++ks)
                wa[tt][ks] = load_w8_f32(wu_f32, (long)drow * RLOW + ks * 32 + 8 * lq);
        }
        f32x4 acc[4] = {{0.f,0.f,0.f,0.f},{0.f,0.f,0.f,0.f},{0.f,0.f,0.f,0.f},{0.f,0.f,0.f,0.f}};
        #pragma unroll
        for (int ks = 0; ks < 4; ++ks)
            #pragma unroll
            for (int tt = 0; tt < 4; ++tt)
                acc[tt] = __builtin_amdgcn_mfma_f32_16x16x32_bf16(wa[tt][ks], hb[ks], acc[tt], 0, 0, 0);
        #pragma unroll
        for (int tt = 0; tt < 4; ++tt) {
            const int dc = d0 + tt * 16 + 4 * lq;
            float4 xf = *(const float4*)(xblk + (long)t * DIMX + dc);
            float4 o;
            o.x = xf.x * invr_t * sigm(acc[tt][0]);
            o.y = xf.y * invr_t * sigm(acc[tt][1]);
            o.z = xf.z * invr_t * sigm(acc[tt][2]);
            o.w = xf.w * invr_t * sigm(acc[tt][3]);
            *(float4*)(outblk + (long)t * DIMX + dc) = o;
        }
    }
}

extern "C" void kernel_launch(void* const* d_in, const int* in_sizes, int n_in,
                              void* d_out, int out_size, void* d_ws, size_t ws_size,
                              hipStream_t stream) {
    const float* x  = (const float*)d_in[0];
    const float* wd = (const float*)d_in[1];   // [128][4096]
    const float* wu = (const float*)d_in[2];   // [4096][128]
    float* out = (float*)d_out;

    const int ntok = in_sizes[0] / DIMX;       // 16384
    const int nblk = ntok / BT;                // 1024

    // ws: wd_frag (1MB) | wu_frag (1MB) | h_ws (4MB) | invr_ws (64KB)
    const size_t need = (size_t)2 * RLOW * DIMX * 2
                      + (size_t)ntok * RLOW * 2
                      + (size_t)ntok * 4;
    if (ws_size >= need) {
        unsigned short* wd_frag = (unsigned short*)d_ws;
        unsigned short* wu_frag = wd_frag + (size_t)RLOW * DIMX;
        unsigned short* h_ws    = wu_frag + (size_t)RLOW * DIMX;
        float*          invr_ws = (float*)(h_ws + (size_t)ntok * RLOW);
        prep_weights_frag<<<512, THREADS, 0, stream>>>(wd, wu, wd_frag, wu_frag);
        down_kernel<<<nblk, THREADS, LDS1_BYTES, stream>>>(x, wd_frag, h_ws, invr_ws);
        up_kernel<<<nblk * 8, THREADS, UP_LDS_BYTES, stream>>>(x, wu_frag, h_ws, invr_ws, out);
    } else {
        fused_fallback<<<nblk, THREADS, LDSF_BYTES, stream>>>(x, wd, wu, out);
    }
}